// Round 7
// baseline (165.161 us; speedup 1.0000x reference)
//
#include <hip/hip_runtime.h>
#include <math.h>
#include <stdint.h>

// ---- static problem sizes ----
#define S_    32        // sentences
#define BV_   16        // videos
#define M_    128       // moments
#define C_    256       // channels
#define NN    4096      // N*N
#define P_    2080      // triu(64) count
#define BP    33280     // BV_*P_
#define NSAMP 512       // neg samples per sentence
#define EQCAP 2048      // tie-buffer capacity

// ---------------- Threefry-2x32 (exact JAX replication, key=(0,42)) -------------
__device__ __forceinline__ uint32_t rotl32(uint32_t x, int n){ return (x<<n) | (x>>(32-n)); }

__device__ __forceinline__ void threefry2x32(uint32_t k0, uint32_t k1, uint32_t &x0, uint32_t &x1){
  uint32_t ks2 = k0 ^ k1 ^ 0x1BD11BDAu;
  x0 += k0; x1 += k1;
  #define TF_R(r) { x0 += x1; x1 = rotl32(x1, r); x1 ^= x0; }
  TF_R(13) TF_R(15) TF_R(26) TF_R(6)
  x0 += k1;  x1 += ks2 + 1u;
  TF_R(17) TF_R(29) TF_R(16) TF_R(24)
  x0 += ks2; x1 += k0 + 2u;
  TF_R(13) TF_R(15) TF_R(26) TF_R(6)
  x0 += k0;  x1 += k1 + 3u;
  TF_R(17) TF_R(29) TF_R(16) TF_R(24)
  x0 += k1;  x1 += ks2 + 4u;
  TF_R(13) TF_R(15) TF_R(26) TF_R(6)
  x0 += ks2; x1 += k0 + 5u;
  #undef TF_R
}

// ============== kernel 1: per-sentence top-2(x4 moments) + pos_vf + qsumT =========
__global__ __launch_bounds__(256) void k_prep(const float* __restrict__ iou2ds,
                                              const float* __restrict__ vfeat,
                                              float* __restrict__ pos_vf,
                                              float* __restrict__ qsumT,
                                              int* __restrict__ counter){
  const int s = blockIdx.x;      // 32
  const int t = threadIdx.x;     // 256
  __shared__ float sv1[256], sv2[256];
  __shared__ int   si1[256], si2[256];
  __shared__ int   fpk_s[8];
  __shared__ float wsum[4];
  __shared__ float s_inv;

  if(s==0 && t==0) *counter = 0;   // re-zeroed every call (replay-safe)

  for(int q=0; q<4; ++q){
    const float* row = iou2ds + (size_t)(s*4 + q)*NN;
    float v1=-1e30f, v2=-1e30f; int i1=0x7FFFFFFF, i2=0x7FFFFFFF;
    for(int f=t; f<NN; f+=256){
      int ti = f>>6, tj = f&63;
      if(tj < ti) continue;
      float v = row[f];
      if(v > v1 || (v == v1 && f < i1)){ v2=v1; i2=i1; v1=v; i1=f; }
      else if(v > v2 || (v == v2 && f < i2)){ v2=v; i2=f; }
    }
    sv1[t]=v1; sv2[t]=v2; si1[t]=i1; si2[t]=i2;
    for(int stp=128; stp>0; stp>>=1){
      __syncthreads();
      if(t < stp){
        float a1=sv1[t], a2=sv2[t]; int x1=si1[t], x2=si2[t];
        float b1=sv1[t+stp], b2=sv2[t+stp]; int y1=si1[t+stp], y2=si2[t+stp];
        float m1v, m2v; int m1i, m2i;
        bool aTop = (a1 > b1) || (a1 == b1 && x1 < y1);
        if(aTop){
          m1v=a1; m1i=x1;
          if((a2 > b1) || (a2 == b1 && x2 < y1)){ m2v=a2; m2i=x2; } else { m2v=b1; m2i=y1; }
        } else {
          m1v=b1; m1i=y1;
          if((b2 > a1) || (b2 == a1 && y2 < x1)){ m2v=b2; m2i=y2; } else { m2v=a1; m2i=x1; }
        }
        sv1[t]=m1v; sv2[t]=m2v; si1[t]=m1i; si2[t]=m2i;
      }
    }
    __syncthreads();
    if(t==0){ fpk_s[q*2+0]=si1[0]; fpk_s[q*2+1]=si2[0]; }
    __syncthreads();
  }

  // gather 8 selected proposal vectors (channel = t), normalize, accumulate qsum
  float v[8];
  #pragma unroll
  for(int r=0;r<8;r++) v[r] = vfeat[((size_t)s*C_ + t)*NN + fpk_s[r]];

  float qs = 0.f;
  for(int r=0; r<8; ++r){
    float ss = v[r]*v[r];
    for(int o=32;o>0;o>>=1) ss += __shfl_down(ss, o, 64);
    if((t&63)==0) wsum[t>>6]=ss;
    __syncthreads();
    if(t==0){
      float tot = wsum[0]+wsum[1]+wsum[2]+wsum[3];
      s_inv = 1.0f / fmaxf(sqrtf(tot), 1e-12f);
    }
    __syncthreads();
    float pv = v[r] * s_inv;
    pos_vf[(size_t)(s*8+r)*C_ + t] = pv;
    qs += pv;
  }
  qsumT[t*32 + s] = qs;
}

// ============== kernel 2: norm + bank fill + fused GEMM/keys ======================
// block (i,b): stage raw 256c x 64j tile, column norms, write normalized bank,
// then compute ukey for its 64 proposals x all 32 sentences (wave w -> 8 sents,
// qsumT base wave-uniform via readfirstlane -> scalar loads).
__global__ __launch_bounds__(256) void k_bankkeys(const float* __restrict__ vfeat,
                                                  const float* __restrict__ qsumT,
                                                  const float* __restrict__ iou2d,
                                                  float* __restrict__ bank,
                                                  unsigned int* __restrict__ ukey){
  extern __shared__ char dyn_sm[];
  float* tile = (float*)dyn_sm;                  // [256][65] raw values
  float* ssp  = (float*)dyn_sm + 256*65;         // [256]
  float* invs = (float*)dyn_sm + 256*65 + 256;   // [64]

  const int i = blockIdx.x;      // triangle row
  const int b = blockIdx.y;      // video
  const int t = threadIdx.x;
  const int j = t & 63, cq = t >> 6;
  const float* basep = vfeat + (size_t)(2*b)*C_*NN + (size_t)i*64;

  float ssq = 0.f;
  for(int it=0; it<64; ++it){
    int cc = it*4 + cq;
    float v = basep[(size_t)cc*NN + j];
    tile[cc*65 + j] = v;
    ssq += v*v;
  }
  ssp[t] = ssq;
  __syncthreads();
  if(t < 64){
    float tot = ssp[t]+ssp[64+t]+ssp[128+t]+ssp[192+t];
    invs[t] = 1.0f/fmaxf(sqrtf(tot), 1e-12f);
  }
  __syncthreads();

  const int start = 64*i - (i*(i-1))/2;
  // write normalized bank rows (jj >= i)
  for(int jj=i; jj<64; ++jj){
    size_t row = (size_t)b*P_ + start + (jj - i);
    bank[row*C_ + t] = tile[t*65 + jj] * invs[jj];
  }

  // fused GEMM: wave w handles sentences sbase..sbase+7 for all 64 columns
  const int lane = t & 63;
  const int sbase = __builtin_amdgcn_readfirstlane((t >> 6) * 8);
  float acc[8];
  #pragma unroll
  for(int k=0;k<8;k++) acc[k]=0.f;
  #pragma unroll 4
  for(int cc=0; cc<256; ++cc){
    float v = tile[cc*65 + lane];
    const float* qc = qsumT + cc*32 + sbase;   // wave-uniform -> scalar loads
    #pragma unroll
    for(int k=0;k<8;k++) acc[k] = fmaf(qc[k], v, acc[k]);
  }

  // epilogue: keys for valid columns (lane >= i)
  if(lane >= i){
    const int jg = b*P_ + start + (lane - i);
    const int fp = i*64 + lane;
    const float iou0 = iou2d[(size_t)(2*b)*NN + fp];
    const float iou1 = iou2d[(size_t)(2*b+1)*NN + fp];
    const float inv_j = invs[lane];
    #pragma unroll 1
    for(int k=0;k<8;k++){
      const int sIdx = sbase + k;
      float fz = 0.0625f*(acc[k]*inv_j) + 0.5f;
      bool pos = ((sIdx>>1)==b) && (((sIdx&1)?iou1:iou0) > 0.5f);
      float val = pos ? 0.f : fz*fz;
      float key;
      if(val > 0.f){
        float logw = logf(fmaxf(val, 1e-30f));
        unsigned int f = (unsigned int)(sIdx*BP + jg);
        const unsigned int HALF = 532480u;     // (S_*BP)/2
        bool second = f >= HALF;
        uint32_t x0 = second ? (f - HALF) : f;
        uint32_t x1 = second ? f : (f + HALF);
        threefry2x32(0u, 42u, x0, x1);
        uint32_t bits = second ? x1 : x0;
        uint32_t fb = (bits >> 9) | 0x3f800000u;
        float f01 = __uint_as_float(fb) - 1.0f;
        const float mn = 1e-7f, mx = 1.0f - 1e-7f;
        float u = fmaxf(mn, f01*(mx-mn) + mn);
        float g = -logf(-logf(u));
        key = logw + g;
      } else {
        key = -INFINITY;
      }
      unsigned int kb = __float_as_uint(key);
      kb = (kb & 0x80000000u) ? ~kb : (kb | 0x80000000u);
      ukey[(size_t)sIdx*BP + jg] = kb;
    }
  }
}

// ============== kernel 3: select (radix, list in LDS) + negsum + loss + final =====
__global__ __launch_bounds__(1024) void k_selneg(const unsigned int* __restrict__ ukey,
                                                 const float* __restrict__ bank,
                                                 const float* __restrict__ pos_vf,
                                                 float* __restrict__ partial,
                                                 int* __restrict__ counter,
                                                 float* __restrict__ out){
  extern __shared__ char dyn_sm[];
  unsigned int* row  = (unsigned int*)dyn_sm;        // [BP]
  unsigned int* hist = (unsigned int*)dyn_sm + BP;   // [256*17]
  int* list_lds = (int*)hist;                        // [512]  (after descent)
  int* eqbuf    = (int*)hist + 512;                  // [EQCAP]
  float* pv     = (float*)dyn_sm;                    // [8][260] (after emit)
  float* hibuf  = (float*)dyn_sm + 4096;             // [512][8] (after emit)
  __shared__ int s_wv[16];
  __shared__ unsigned int s_prefix;
  __shared__ int s_cntgt, s_need, s_eq;
  __shared__ float red[8][8];
  __shared__ float ns_s[8];

  const int s = blockIdx.x;
  const int t = threadIdx.x;
  const int lane = t & 63;
  const int col  = t & 15;
  const unsigned int* grow = ukey + (size_t)s*BP;

  unsigned int prefix = 0, pmask = 0;
  int need = NSAMP, cnt_gt = 0;

  for(int lev=0; lev<4; ++lev){
    const int shift = 24 - 8*lev;
    for(int k=t; k<256*17; k+=1024) hist[k] = 0;
    __syncthreads();
    if(lev==0){
      for(int k=t; k<BP; k+=1024){
        unsigned int u = grow[k];
        row[k] = u;
        atomicAdd(&hist[(u >> 24)*17 + col], 1u);
      }
    } else {
      for(int k=t; k<BP; k+=1024){
        unsigned int u = row[k];
        if((u & pmask) == prefix)
          atomicAdd(&hist[((u >> shift) & 255u)*17 + col], 1u);
      }
    }
    __syncthreads();
    int v = 0; unsigned int h = 0;
    if(t < 256){
      const unsigned int* hr = hist + t*17;
      #pragma unroll
      for(int c=0;c<16;c++) h += hr[c];
      v = (int)h;
      #pragma unroll
      for(int off=1; off<64; off<<=1){
        int src = lane + off;
        int o = __shfl(v, (src<64)?src:lane, 64);
        v += (src<64)? o : 0;
      }
      if(lane==0) s_wv[t>>6] = v;
    }
    __syncthreads();
    if(t < 256){
      int wv4 = t>>6, tail = 0;
      for(int w2=wv4+1; w2<4; ++w2) tail += s_wv[w2];
      int Sb  = v + tail;
      int Sb1 = Sb - (int)h;
      if(Sb >= need && Sb1 < need){
        s_prefix = prefix | ((unsigned int)t << shift);
        s_cntgt  = cnt_gt + Sb1;
        s_need   = need - Sb1;
      }
    }
    __syncthreads();
    prefix = s_prefix; cnt_gt = s_cntgt; need = s_need;
    pmask |= (0xFFu << shift);
    __syncthreads();
  }

  const unsigned int ustar = prefix;
  const int quota = need;

  if(t==0) s_eq = 0;
  __syncthreads();

  // deterministic gt emit (stripe scan), eq indices buffered
  int gtc = 0;
  for(int k=t; k<BP; k+=1024) gtc += (row[k] > ustar) ? 1 : 0;
  int vg = gtc;
  #pragma unroll
  for(int off=1; off<64; off<<=1){
    int src = lane - off;
    int o = __shfl(vg, (src>=0)?src:lane, 64);
    vg += (src>=0)? o : 0;
  }
  const int wv16 = t>>6;
  if(lane==63) s_wv[wv16] = vg;
  __syncthreads();
  int base2 = 0;
  for(int w2=0; w2<wv16; ++w2) base2 += s_wv[w2];
  int gi = base2 + vg - gtc;
  for(int k=t; k<BP; k+=1024){
    unsigned int u = row[k];
    if(u > ustar){
      list_lds[gi++] = k;
    } else if(u == ustar){
      int e = atomicAdd(&s_eq, 1);
      if(e < EQCAP) eqbuf[e] = k;
    }
  }
  __syncthreads();
  const int eqn = s_eq;
  if(eqn <= EQCAP){
    for(int i2=t; i2<eqn; i2+=1024){
      int ii = eqbuf[i2];
      int r = 0;
      for(int j2=0; j2<eqn; ++j2) r += (eqbuf[j2] < ii) ? 1 : 0;
      if(r < quota) list_lds[cnt_gt + r] = ii;
    }
  } else {
    if(t==0){
      int taken = 0;
      for(int idx=0; idx<BP && taken<quota; ++idx)
        if(row[idx]==ustar){ list_lds[cnt_gt + taken] = idx; ++taken; }
    }
  }
  __syncthreads();

  // ---- negsum + loss (row region reused for pv / hibuf) ----
  for(int idx=t; idx<8*C_; idx+=1024){
    int a = idx>>8, c = idx&255;
    pv[a*260 + c] = pos_vf[(size_t)(s*8)*C_ + idx];
  }
  __syncthreads();

  const int t0 = t & 511, half = t >> 9;
  const int jn = list_lds[t0];
  const float4* bp = (const float4*)(bank + (size_t)jn*C_ + half*128);
  float acc[8] = {0,0,0,0,0,0,0,0};
  for(int c4=0; c4<32; ++c4){
    float4 bv = bp[c4];
    #pragma unroll
    for(int a=0;a<8;a++){
      const float* pva = pv + a*260 + half*128 + c4*4;
      acc[a] += bv.x*pva[0] + bv.y*pva[1] + bv.z*pva[2] + bv.w*pva[3];
    }
  }
  if(half==1){
    #pragma unroll
    for(int a=0;a<8;a++) hibuf[t0*8 + a] = acc[a];
  }
  __syncthreads();
  if(t < 512){
    float e[8];
    #pragma unroll
    for(int a=0;a<8;a++){
      float accf = acc[a] + hibuf[t0*8 + a];
      float v = expf(accf/0.1f);
      for(int o=32;o>0;o>>=1) v += __shfl_down(v, o, 64);
      e[a] = v;
    }
    int wv = t>>6;                       // 0..7
    if((t&63)==0){
      #pragma unroll
      for(int a=0;a<8;a++) red[wv][a]=e[a];
    }
  }
  __syncthreads();
  if(t < 8){
    float tot = 0.f;
    for(int w=0; w<8; w++) tot += red[w][t];
    ns_s[t] = tot;
  }
  __syncthreads();

  if(t < 64){
    int a = t>>3, b2 = t&7;
    float dot = 0.f;
    for(int c=0;c<C_;c++) dot += pv[a*260+c]*pv[b2*260+c];
    float pl = dot/0.1f;
    float term = logf(expf(pl) + ns_s[a]) - pl;
    for(int o=32;o>0;o>>=1) term += __shfl_down(term, o, 64);
    if(t==0){
      atomicExch(&partial[s], term);     // device-scope store (cross-XCD safe)
      __threadfence();
      int old = atomicAdd(counter, 1);
      if(old == 31){
        __threadfence();
        float sum = 0.f;
        for(int i2=0;i2<32;i2++) sum += atomicAdd(&partial[i2], 0.0f);  // coherent read
        float loss = sum / 2048.0f;
        out[0] = loss * 1.0f;            // WEIGHT = 1.0
        out[1] = loss;
      }
    }
  }
}

// ======================= host launcher =============================================
extern "C" void kernel_launch(void* const* d_in, const int* in_sizes, int n_in,
                              void* d_out, int out_size, void* d_ws, size_t ws_size,
                              hipStream_t stream) {
  const float* video_feats = (const float*)d_in[0];
  const float* iou2d  = (const float*)d_in[4];
  const float* iou2ds = (const float*)d_in[5];

  // workspace layout (bytes, 256-aligned)
  const size_t o_pvf   = 0;            // 256*256 f32 (262144)
  const size_t o_qsT   = 262144;       // 256*32 f32 (32768)
  const size_t o_bank  = 294912;       // 33280*256 f32 (34078720)
  const size_t o_ukey  = 34373632;     // 32*33280 u32 (4259840)
  const size_t o_part  = 38633472;     // 32 f32 (128)
  const size_t o_cnt   = 38633600;     // 1 i32
  const size_t NEED    = 38633728;
  if (ws_size < NEED) return;

  char* w = (char*)d_ws;
  float*        pos_vf  = (float*)(w + o_pvf);
  float*        qsumT   = (float*)(w + o_qsT);
  float*        bank    = (float*)(w + o_bank);
  unsigned int* ukey    = (unsigned int*)(w + o_ukey);
  float*        part    = (float*)(w + o_part);
  int*          counter = (int*)(w + o_cnt);
  float*        out     = (float*)d_out;

  const int BK_LDS  = (256*65 + 256 + 64) * 4;   // 67840
  const int SEL_LDS = (BP + 256*17) * 4;         // 150528
  static bool attr_set = false;
  if(!attr_set){
    (void)hipFuncSetAttribute((const void*)k_bankkeys,
                              hipFuncAttributeMaxDynamicSharedMemorySize, BK_LDS);
    (void)hipFuncSetAttribute((const void*)k_selneg,
                              hipFuncAttributeMaxDynamicSharedMemorySize, SEL_LDS);
    attr_set = true;
  }

  k_prep<<<32, 256, 0, stream>>>(iou2ds, video_feats, pos_vf, qsumT, counter);
  k_bankkeys<<<dim3(64,16), 256, BK_LDS, stream>>>(video_feats, qsumT, iou2d, bank, ukey);
  k_selneg<<<32, 1024, SEL_LDS, stream>>>(ukey, bank, pos_vf, part, counter, out);
}